// Round 6
// baseline (547.832 us; speedup 1.0000x reference)
//
#include <hip/hip_runtime.h>

// Bidirectional LSTM, B=256, T=1024, V=6, D=64, U=64; out = last-step
// concat(h_f, h_b) @ Wd + bd, shape (B,1).
// Reductions: backward dir = ONE step from h0=0 (Wr_b dead); V=6 -> xproj is
// a 6-entry table (batch-INDEPENDENT); mask = 6-bit scalar.
// R12: 296us. R13-R15 (1-wave resident weights): 400-460us, RA spill.
// R16 (col/lane + LDS act exch): 360us. R17 (quad-gate + DPP act exch): 300us.
// R12/R16/R17 all converge to ~690-840 cyc/step -> the floor is the SERIAL
// latency chain (barrier -> h-read ~130 -> dot dep ~70 -> act ~50 -> c/h ~60
// -> h-write -> barrier), not issue (~110cyc/SIMD).
// R18: amortize the chain across the batch dim: TWO batches per block sharing
// the same 32 resident weight VGPRs. The two recurrences interleave in each
// other's latency gaps; barrier + LDS latency paid once per step for both.
// proj table shared (emb-only); tokens/h/c/out duplicated. Grid 128 blocks.
// Loop-carried regs stay small (32 w + ~16 state) -> no R15-style spill.

constexpr int kB = 256;
constexpr int kT = 1024;
constexpr int kV = 6;
constexpr int kD = 64;
constexpr int kU = 64;
constexpr int kG = 256; // 4*U gate columns

#define LOG2E 1.44269504f

typedef _Float16 v2h __attribute__((ext_vector_type(2)));

template <int CTRL>
__device__ __forceinline__ float dppf(float x) {
    return __int_as_float(
        __builtin_amdgcn_mov_dpp(__float_as_int(x), CTRL, 0xF, 0xF, true));
}
constexpr int kBc0 = 0x00, kBc1 = 0x55, kBc2 = 0xAA, kBc3 = 0xFF; // quad bcast

__device__ __forceinline__ float fast_rcp(float x) { return __builtin_amdgcn_rcpf(x); }
__device__ __forceinline__ float exp2_f(float x)   { return __builtin_amdgcn_exp2f(x); }
__device__ __forceinline__ float sig_f(float z)  { return fast_rcp(1.0f + exp2_f(-LOG2E * z)); }
__device__ __forceinline__ float tanh_f(float z) { return 2.0f * fast_rcp(1.0f + exp2_f(-2.0f * LOG2E * z)) - 1.0f; }

__device__ __forceinline__ v2h as_v2h(float x) { return __builtin_bit_cast(v2h, x); }

__global__ __launch_bounds__(256)
__attribute__((amdgpu_waves_per_eu(1, 1)))
void bilstm_last_kernel(
    const int*   __restrict__ tokens, // (B,T)
    const float* __restrict__ emb,    // (6,64)
    const float* __restrict__ Wk_f,   // (64,256)
    const float* __restrict__ Wr_f,   // (64,256)
    const float* __restrict__ b_f,    // (256)
    const float* __restrict__ Wk_b,   // (64,256)
    const float* __restrict__ b_b,    // (256)
    const float* __restrict__ Wd,     // (128)
    const float* __restrict__ bd,     // (1)
    float*       __restrict__ out)    // (B)
{
    __shared__ float s_emb[kV * kD];
    __shared__ float __align__(16) s_projP[kV * kG];   // [v][tid] shared by both batches
    __shared__ int   __align__(16) s_tok[2][kT];
    __shared__ _Float16 __align__(16) s_hh[2][2][kU];  // [buf][batch][unit]
    __shared__ float s_red[2][4];

    const int bP  = blockIdx.x * 2;
    const int bQ  = bP + 1;
    const int tid = threadIdx.x;
    const int l   = tid & 63;        // lane in wave
    const int wv  = tid >> 6;        // wave id
    const int s   = l & 3;           // gate (0=i,1=f,2=g,3=o)
    const int k   = l >> 2;          // quad id 0..15
    const int u   = wv * 16 + k;     // unit owned by this quad
    const int col = s * kU + u;      // owned gate column in (.,256) matrices

    // ---- stage emb + tokens; zero h buffers ----
    for (int i = tid; i < kV * kD; i += 256) s_emb[i] = emb[i];
    ((int4*)s_tok[0])[tid] = ((const int4*)(tokens + bP * kT))[tid];
    ((int4*)s_tok[1])[tid] = ((const int4*)(tokens + bQ * kT))[tid];
    ((_Float16*)s_hh)[tid] = (_Float16)0.f;   // 2*2*64 = 256 entries
    __syncthreads();   // emb + tokens visible

    // ---- 6-bit mask, scalarized (emb-based, batch-independent) ----
    unsigned int mbv = 0;
#pragma unroll
    for (int v = 0; v < kV; ++v) {
        const unsigned long long bb = __ballot(s_emb[v * kD + l] != 0.0f);
        mbv |= (bb != 0ull) ? (1u << v) : 0u;
    }
    const unsigned int smb = __builtin_amdgcn_readfirstlane(mbv);

    const int tokLP = __builtin_amdgcn_readfirstlane(s_tok[0][kT - 1]);
    const int tokLQ = __builtin_amdgcn_readfirstlane(s_tok[1][kT - 1]);

    // ---- proj: own forward column for all 6 tokens (shared table) + the two
    //      backward columns (one per batch, at each batch's last token) ----
    float abP, abQ;
    {
        float afv[kV];
        const float bf = b_f[col];
#pragma unroll
        for (int v = 0; v < kV; ++v) afv[v] = bf;
        abP = b_b[col]; abQ = abP;
#pragma unroll 4
        for (int d = 0; d < kD; ++d) {
            const float wkf = Wk_f[d * kG + col];
            const float wkb = Wk_b[d * kG + col];
            afv[0] = fmaf(s_emb[0 * kD + d], wkf, afv[0]);
            afv[1] = fmaf(s_emb[1 * kD + d], wkf, afv[1]);
            afv[2] = fmaf(s_emb[2 * kD + d], wkf, afv[2]);
            afv[3] = fmaf(s_emb[3 * kD + d], wkf, afv[3]);
            afv[4] = fmaf(s_emb[4 * kD + d], wkf, afv[4]);
            afv[5] = fmaf(s_emb[5 * kD + d], wkf, afv[5]);
            abP    = fmaf(s_emb[tokLP * kD + d], wkb, abP);
            abQ    = fmaf(s_emb[tokLQ * kD + d], wkb, abQ);
        }
#pragma unroll
        for (int v = 0; v < kV; ++v) s_projP[v * kG + tid] = afv[v];
    }

    // per-lane activation constants: gate s==2 is tanh, others sigmoid
    const bool  isg    = (s == 2);
    const float aScale = isg ? -2.0f * LOG2E : -LOG2E;
    const float aMul   = isg ? 2.0f : 1.0f;
    const float aAdd   = isg ? -1.0f : 0.0f;

    // ---- backward single step per batch via quad DPP (c0=0 -> f dead) ----
    float hbP, hbQ;
    {
        const float eP = exp2_f(abP * aScale);
        const float rP = fast_rcp(1.0f + eP);
        const float aP = fmaf(rP, aMul, aAdd);
        const float cbP = dppf<kBc0>(aP) * dppf<kBc2>(aP);
        const float hP  = dppf<kBc3>(aP) * tanh_f(cbP);
        hbP = ((smb >> tokLP) & 1) ? hP : 0.0f;
        const float eQ = exp2_f(abQ * aScale);
        const float rQ = fast_rcp(1.0f + eQ);
        const float aQ = fmaf(rQ, aMul, aAdd);
        const float cbQ = dppf<kBc0>(aQ) * dppf<kBc2>(aQ);
        const float hQ  = dppf<kBc3>(aQ) * tanh_f(cbQ);
        hbQ = ((smb >> tokLQ) & 1) ? hQ : 0.0f;
    }

    // ---- recurrent weights: own column col as 32 named f16 pairs ----
#define DECLW(p)                                                              \
    v2h wh_##p;                                                               \
    wh_##p.x = (_Float16)Wr_f[(2 * (p) + 0) * kG + col];                      \
    wh_##p.y = (_Float16)Wr_f[(2 * (p) + 1) * kG + col];
    DECLW(0)  DECLW(1)  DECLW(2)  DECLW(3)  DECLW(4)  DECLW(5)  DECLW(6)  DECLW(7)
    DECLW(8)  DECLW(9)  DECLW(10) DECLW(11) DECLW(12) DECLW(13) DECLW(14) DECLW(15)
    DECLW(16) DECLW(17) DECLW(18) DECLW(19) DECLW(20) DECLW(21) DECLW(22) DECLW(23)
    DECLW(24) DECLW(25) DECLW(26) DECLW(27) DECLW(28) DECLW(29) DECLW(30) DECLW(31)
#undef DECLW

    float cP = 0.0f, hregP = 0.0f;
    float cQ = 0.0f, hregQ = 0.0f;

    // ---- scalar token pipelines, depth 2, per batch ----
    int stok0P = __builtin_amdgcn_readfirstlane(s_tok[0][0]);
    int stok0Q = __builtin_amdgcn_readfirstlane(s_tok[1][0]);
    float zcurP = s_projP[stok0P * kG + tid];
    float zcurQ = s_projP[stok0Q * kG + tid];
    int mskcP = (smb >> stok0P) & 1;
    int mskcQ = (smb >> stok0Q) & 1;
    int stokAP = __builtin_amdgcn_readfirstlane(s_tok[0][1]);
    int stokAQ = __builtin_amdgcn_readfirstlane(s_tok[1][1]);

    // unpack one batch's h (broadcast b128 reads, conflict-free)
#define HUNPACK(S, RP, Bi)                                                    \
    const float4* hp##S = (const float4*)s_hh[RP][Bi];                        \
    const float4 S##v0 = hp##S[0], S##v1 = hp##S[1];                          \
    const float4 S##v2 = hp##S[2], S##v3 = hp##S[3];                          \
    const float4 S##v4 = hp##S[4], S##v5 = hp##S[5];                          \
    const float4 S##v6 = hp##S[6], S##v7 = hp##S[7];                          \
    const v2h S##_0  = as_v2h(S##v0.x), S##_1  = as_v2h(S##v0.y);             \
    const v2h S##_2  = as_v2h(S##v0.z), S##_3  = as_v2h(S##v0.w);             \
    const v2h S##_4  = as_v2h(S##v1.x), S##_5  = as_v2h(S##v1.y);             \
    const v2h S##_6  = as_v2h(S##v1.z), S##_7  = as_v2h(S##v1.w);             \
    const v2h S##_8  = as_v2h(S##v2.x), S##_9  = as_v2h(S##v2.y);             \
    const v2h S##_10 = as_v2h(S##v2.z), S##_11 = as_v2h(S##v2.w);             \
    const v2h S##_12 = as_v2h(S##v3.x), S##_13 = as_v2h(S##v3.y);             \
    const v2h S##_14 = as_v2h(S##v3.z), S##_15 = as_v2h(S##v3.w);             \
    const v2h S##_16 = as_v2h(S##v4.x), S##_17 = as_v2h(S##v4.y);             \
    const v2h S##_18 = as_v2h(S##v4.z), S##_19 = as_v2h(S##v4.w);             \
    const v2h S##_20 = as_v2h(S##v5.x), S##_21 = as_v2h(S##v5.y);             \
    const v2h S##_22 = as_v2h(S##v5.z), S##_23 = as_v2h(S##v5.w);             \
    const v2h S##_24 = as_v2h(S##v6.x), S##_25 = as_v2h(S##v6.y);             \
    const v2h S##_26 = as_v2h(S##v6.z), S##_27 = as_v2h(S##v6.w);             \
    const v2h S##_28 = as_v2h(S##v7.x), S##_29 = as_v2h(S##v7.y);             \
    const v2h S##_30 = as_v2h(S##v7.z), S##_31 = as_v2h(S##v7.w);

    // full 64-len dot: 4 independent chains of depth 8
#define DOT64(S, seed, zout)                                                  \
    {                                                                         \
        float pa = __builtin_amdgcn_fdot2(S##_0,  wh_0,  (seed), false);      \
        float pb = __builtin_amdgcn_fdot2(S##_1,  wh_1,  0.0f, false);        \
        float pc = __builtin_amdgcn_fdot2(S##_2,  wh_2,  0.0f, false);        \
        float pd = __builtin_amdgcn_fdot2(S##_3,  wh_3,  0.0f, false);        \
        pa = __builtin_amdgcn_fdot2(S##_4,  wh_4,  pa, false);                \
        pb = __builtin_amdgcn_fdot2(S##_5,  wh_5,  pb, false);                \
        pc = __builtin_amdgcn_fdot2(S##_6,  wh_6,  pc, false);                \
        pd = __builtin_amdgcn_fdot2(S##_7,  wh_7,  pd, false);                \
        pa = __builtin_amdgcn_fdot2(S##_8,  wh_8,  pa, false);                \
        pb = __builtin_amdgcn_fdot2(S##_9,  wh_9,  pb, false);                \
        pc = __builtin_amdgcn_fdot2(S##_10, wh_10, pc, false);                \
        pd = __builtin_amdgcn_fdot2(S##_11, wh_11, pd, false);                \
        pa = __builtin_amdgcn_fdot2(S##_12, wh_12, pa, false);                \
        pb = __builtin_amdgcn_fdot2(S##_13, wh_13, pb, false);                \
        pc = __builtin_amdgcn_fdot2(S##_14, wh_14, pc, false);                \
        pd = __builtin_amdgcn_fdot2(S##_15, wh_15, pd, false);                \
        pa = __builtin_amdgcn_fdot2(S##_16, wh_16, pa, false);                \
        pb = __builtin_amdgcn_fdot2(S##_17, wh_17, pb, false);                \
        pc = __builtin_amdgcn_fdot2(S##_18, wh_18, pc, false);                \
        pd = __builtin_amdgcn_fdot2(S##_19, wh_19, pd, false);                \
        pa = __builtin_amdgcn_fdot2(S##_20, wh_20, pa, false);                \
        pb = __builtin_amdgcn_fdot2(S##_21, wh_21, pb, false);                \
        pc = __builtin_amdgcn_fdot2(S##_22, wh_22, pc, false);                \
        pd = __builtin_amdgcn_fdot2(S##_23, wh_23, pd, false);                \
        pa = __builtin_amdgcn_fdot2(S##_24, wh_24, pa, false);                \
        pb = __builtin_amdgcn_fdot2(S##_25, wh_25, pb, false);                \
        pc = __builtin_amdgcn_fdot2(S##_26, wh_26, pc, false);                \
        pd = __builtin_amdgcn_fdot2(S##_27, wh_27, pd, false);                \
        pa = __builtin_amdgcn_fdot2(S##_28, wh_28, pa, false);                \
        pb = __builtin_amdgcn_fdot2(S##_29, wh_29, pb, false);                \
        pc = __builtin_amdgcn_fdot2(S##_30, wh_30, pc, false);                \
        pd = __builtin_amdgcn_fdot2(S##_31, wh_31, pd, false);                \
        zout = (pa + pb) + (pc + pd);                                         \
    }

    // own-gate activation + quad DPP exchange + c/h update + h publish
#define GATEUPD(S, z, mskc, c, hreg, WP, Bi)                                  \
    {                                                                         \
        const float e_ = exp2_f((z) * aScale);                                \
        const float r_ = fast_rcp(1.0f + e_);                                 \
        const float a_ = fmaf(r_, aMul, aAdd);                                \
        const float ai_ = dppf<kBc0>(a_);                                     \
        const float af_ = dppf<kBc1>(a_);                                     \
        const float ag_ = dppf<kBc2>(a_);                                     \
        const float ao_ = dppf<kBc3>(a_);                                     \
        const float cn_ = fmaf(af_, c, ai_ * ag_);                            \
        const float hn_ = ao_ * tanh_f(cn_);                                  \
        if (mskc) { c = cn_; hreg = hn_; }   /* uniform branch */             \
        if (s == 0) s_hh[WP][Bi][u] = (_Float16)hreg;                         \
    }

    // h-buffer safety: step t reads s_hh[RP] before its barrier (reads drain
    // at the barrier's lgkmcnt(0)); buffer RP is rewritten only in step t+1
    // after that barrier. Double-buffer + 1 barrier/step is safe.
#define STEP(RP, WP, TT)                                                      \
    {                                                                         \
        HUNPACK(P, RP, 0)                                                     \
        HUNPACK(Q, RP, 1)                                                     \
        const int   vtokBP = s_tok[0][((TT) + 2) & (kT - 1)];                 \
        const int   vtokBQ = s_tok[1][((TT) + 2) & (kT - 1)];                 \
        const float znextP = s_projP[stokAP * kG + tid];                      \
        const float znextQ = s_projP[stokAQ * kG + tid];                      \
        const int   msknP  = (int)((smb >> stokAP) & 1);                      \
        const int   msknQ  = (int)((smb >> stokAQ) & 1);                      \
        float zP, zQ;                                                         \
        DOT64(P, zcurP, zP)                                                   \
        DOT64(Q, zcurQ, zQ)                                                   \
        GATEUPD(P, zP, mskcP, cP, hregP, WP, 0)                               \
        GATEUPD(Q, zQ, mskcQ, cQ, hregQ, WP, 1)                               \
        __syncthreads();                                                      \
        zcurP = znextP; mskcP = msknP;                                        \
        zcurQ = znextQ; mskcQ = msknQ;                                        \
        stokAP = __builtin_amdgcn_readfirstlane(vtokBP);                      \
        stokAQ = __builtin_amdgcn_readfirstlane(vtokBQ);                      \
    }

#pragma unroll 1
    for (int t = 0; t < kT; t += 2) {
        STEP(0, 1, t)
        STEP(1, 0, t + 1)
    }
#undef STEP
#undef GATEUPD
#undef DOT64
#undef HUNPACK

    // ---- epilogue: quad lane s==0 holds exact f32 h_f[u], h_b[u] per batch ----
    {
        float v = (s == 0) ? (hregP * Wd[u] + hbP * Wd[kU + u]) : 0.0f;
#pragma unroll
        for (int off = 32; off > 0; off >>= 1) v += __shfl_down(v, off, 64);
        if (l == 0) s_red[0][wv] = v;
        float w = (s == 0) ? (hregQ * Wd[u] + hbQ * Wd[kU + u]) : 0.0f;
#pragma unroll
        for (int off = 32; off > 0; off >>= 1) w += __shfl_down(w, off, 64);
        if (l == 0) s_red[1][wv] = w;
    }
    __syncthreads();
    if (tid == 0) {
        out[bP] = (s_red[0][0] + s_red[0][1]) + (s_red[0][2] + s_red[0][3]) + bd[0];
        out[bQ] = (s_red[1][0] + s_red[1][1]) + (s_red[1][2] + s_red[1][3]) + bd[0];
    }
}

extern "C" void kernel_launch(void* const* d_in, const int* in_sizes, int n_in,
                              void* d_out, int out_size, void* d_ws, size_t ws_size,
                              hipStream_t stream) {
    const int*   tokens = (const int*)d_in[0];
    const float* emb    = (const float*)d_in[1];
    const float* Wk_f   = (const float*)d_in[2];
    const float* Wr_f   = (const float*)d_in[3];
    const float* b_f    = (const float*)d_in[4];
    const float* Wk_b   = (const float*)d_in[5];
    // d_in[6] = Wr_b: unused (backward runs one step from h0=0)
    const float* b_b    = (const float*)d_in[7];
    const float* Wd     = (const float*)d_in[8];
    const float* bd     = (const float*)d_in[9];
    float* out = (float*)d_out;

    bilstm_last_kernel<<<kB / 2, 256, 0, stream>>>(
        tokens, emb, Wk_f, Wr_f, b_f, Wk_b, b_b, Wd, bd, out);
}

// Round 7
// 402.738 us; speedup vs baseline: 1.3603x; 1.3603x over previous
//
#include <hip/hip_runtime.h>

// Bidirectional LSTM, B=256, T=1024, V=6, D=64, U=64; out = last-step
// concat(h_f, h_b) @ Wd + bd, shape (B,1).
// Reductions: backward dir = ONE step from h0=0 (Wr_b dead); V=6 -> xproj is
// a 6-entry per-column table; mask = 6-bit scalar.
// History: R12 296us / R13-15 (reg-resident weights) 400-460us RA-spill /
// R16 360us / R17 300us / R18 (2 batches) 495us.
// DS-op model (fit R16/R17/R18): cyc/step ~= 350 + 8 * (DS wave-instrs per
// CU). R17 = 44 DS (4 waves x full-h 8xb128 broadcast + misc) -> 700cyc.
// The kernel is LDS-ISSUE-THROUGHPUT bound, not latency bound.
// R19: minimize DS. Per wave/step: 2xb128 h-read (lane reads only its quad's
// 32B K-slice, R12 layout), 1 h-write, 0.5 token b64. Everything else in
// registers: xproj = 6 per-lane regs selected by uniform token (cndmask
// chain, computed 2 steps ahead in the shadow); no s_projP, no per-step
// znext/tok DS reads. Compute = R12's verified 4-gate partial dots +
// transpose-butterfly + one act/lane + quad DPP bcast + redundant c/h.
// DS: 44 -> 14/step/CU. Predicted ~480-540 cyc/step.

constexpr int kB = 256;
constexpr int kT = 1024;
constexpr int kV = 6;
constexpr int kD = 64;
constexpr int kU = 64;
constexpr int kG = 256; // 4*U gate columns

#define LOG2E 1.44269504f

typedef _Float16 v2h __attribute__((ext_vector_type(2)));

template <int CTRL>
__device__ __forceinline__ float dppf(float x) {
    return __int_as_float(
        __builtin_amdgcn_mov_dpp(__float_as_int(x), CTRL, 0xF, 0xF, true));
}
constexpr int kXor1 = 0xB1; // quad_perm(1,0,3,2)
constexpr int kXor2 = 0x4E; // quad_perm(2,3,0,1)
constexpr int kBc0 = 0x00, kBc1 = 0x55, kBc2 = 0xAA, kBc3 = 0xFF;

__device__ __forceinline__ float fast_rcp(float x) { return __builtin_amdgcn_rcpf(x); }
__device__ __forceinline__ float exp2_f(float x)   { return __builtin_amdgcn_exp2f(x); }
__device__ __forceinline__ float tanh_f(float z) { return 2.0f * fast_rcp(1.0f + exp2_f(-2.0f * LOG2E * z)) - 1.0f; }

__device__ __forceinline__ v2h as_v2h(float x) { return __builtin_bit_cast(v2h, x); }

__global__ __launch_bounds__(256)
__attribute__((amdgpu_waves_per_eu(1, 1)))
void bilstm_last_kernel(
    const int*   __restrict__ tokens, // (B,T)
    const float* __restrict__ emb,    // (6,64)
    const float* __restrict__ Wk_f,   // (64,256)
    const float* __restrict__ Wr_f,   // (64,256)
    const float* __restrict__ b_f,    // (256)
    const float* __restrict__ Wk_b,   // (64,256)
    const float* __restrict__ b_b,    // (256)
    const float* __restrict__ Wd,     // (128)
    const float* __restrict__ bd,     // (1)
    float*       __restrict__ out)    // (B)
{
    __shared__ float s_emb[kV * kD];
    __shared__ int   __align__(16) s_tok[kT];
    __shared__ _Float16 __align__(16) s_hh[2][kU];   // double-buffered h (f16)
    __shared__ float s_red[4];

    const int b   = blockIdx.x;
    const int tid = threadIdx.x;
    const int l   = tid & 63;        // lane in wave
    const int wv  = tid >> 6;        // wave id
    const int s   = l & 3;           // gate AND h-slice (0=i,1=f,2=g,3=o)
    const int k   = l >> 2;          // quad id 0..15
    const int u   = wv * 16 + k;     // unit owned by this quad
    const int col = s * kU + u;      // owned gate column in (.,256) matrices

    // ---- stage emb + tokens; zero h buffers ----
    for (int i = tid; i < kV * kD; i += 256) s_emb[i] = emb[i];
    ((int4*)s_tok)[tid] = ((const int4*)(tokens + b * kT))[tid];
    if (tid < 2 * kU) ((_Float16*)s_hh)[tid] = (_Float16)0.f;
    __syncthreads();   // emb + tokens visible

    // ---- 6-bit mask, scalarized: bit v = any(emb[v][:] != 0) ----
    unsigned int mbv = 0;
#pragma unroll
    for (int v = 0; v < kV; ++v) {
        const unsigned long long bb = __ballot(s_emb[v * kD + l] != 0.0f);
        mbv |= (bb != 0ull) ? (1u << v) : 0u;
    }
    const unsigned int smb = __builtin_amdgcn_readfirstlane(mbv);

    const int tokL = __builtin_amdgcn_readfirstlane(s_tok[kT - 1]);

    // per-lane activation constants: gate s==2 is tanh, others sigmoid
    const bool  isg    = (s == 2);
    const float aScale = isg ? -2.0f * LOG2E : -LOG2E;
    const float aMul   = isg ? 2.0f : 1.0f;
    const float aAdd   = isg ? -1.0f : 0.0f;

    // ---- proj for OWN column col, all 6 tokens -> kept in 6 REGISTERS ----
    float pf0, pf1, pf2, pf3, pf4, pf5;
    float ab;
    {
        float afv[kV];
        const float bf = b_f[col];
#pragma unroll
        for (int v = 0; v < kV; ++v) afv[v] = bf;
        ab = b_b[col];
#pragma unroll 4
        for (int d = 0; d < kD; ++d) {
            const float wkf = Wk_f[d * kG + col];
            const float wkb = Wk_b[d * kG + col];
            afv[0] = fmaf(s_emb[0 * kD + d], wkf, afv[0]);
            afv[1] = fmaf(s_emb[1 * kD + d], wkf, afv[1]);
            afv[2] = fmaf(s_emb[2 * kD + d], wkf, afv[2]);
            afv[3] = fmaf(s_emb[3 * kD + d], wkf, afv[3]);
            afv[4] = fmaf(s_emb[4 * kD + d], wkf, afv[4]);
            afv[5] = fmaf(s_emb[5 * kD + d], wkf, afv[5]);
            ab     = fmaf(s_emb[tokL * kD + d], wkb, ab);
        }
        pf0 = afv[0]; pf1 = afv[1]; pf2 = afv[2];
        pf3 = afv[3]; pf4 = afv[4]; pf5 = afv[5];
    }
    // uniform-token select of the own-column proj value (pure VALU, no LDS)
    auto sel6 = [&](int t) -> float {
        return t == 0 ? pf0 : t == 1 ? pf1 : t == 2 ? pf2
             : t == 3 ? pf3 : t == 4 ? pf4 : pf5;
    };

    // ---- backward single step via quad DPP (c0=0 -> f dead) ----
    float hb_val;
    {
        const float e = exp2_f(ab * aScale);
        const float r = fast_rcp(1.0f + e);
        const float a = fmaf(r, aMul, aAdd);
        const float cb = dppf<kBc0>(a) * dppf<kBc2>(a);
        const float hb = dppf<kBc3>(a) * tanh_f(cb);
        hb_val = ((smb >> tokL) & 1) ? hb : 0.0f;
    }

    // ---- recurrent weights: K-slice s of own unit's 4 gate columns ----
#define DECLH(g, p)                                                           \
    v2h wh##g##_##p;                                                          \
    wh##g##_##p.x = (_Float16)Wr_f[(16 * s + 2 * (p) + 0) * kG + ((g) * 64 + u)]; \
    wh##g##_##p.y = (_Float16)Wr_f[(16 * s + 2 * (p) + 1) * kG + ((g) * 64 + u)];
    DECLH(0,0) DECLH(0,1) DECLH(0,2) DECLH(0,3) DECLH(0,4) DECLH(0,5) DECLH(0,6) DECLH(0,7)
    DECLH(1,0) DECLH(1,1) DECLH(1,2) DECLH(1,3) DECLH(1,4) DECLH(1,5) DECLH(1,6) DECLH(1,7)
    DECLH(2,0) DECLH(2,1) DECLH(2,2) DECLH(2,3) DECLH(2,4) DECLH(2,5) DECLH(2,6) DECLH(2,7)
    DECLH(3,0) DECLH(3,1) DECLH(3,2) DECLH(3,3) DECLH(3,4) DECLH(3,5) DECLH(3,6) DECLH(3,7)
#undef DECLH

    float c = 0.0f, hreg = 0.0f;

    // ---- scalar token pipeline: steps t,t+1 ready; t+2,t+3 scalars held ----
    int st0 = __builtin_amdgcn_readfirstlane(s_tok[0]);
    int st1 = __builtin_amdgcn_readfirstlane(s_tok[1]);
    int st2 = __builtin_amdgcn_readfirstlane(s_tok[2]);
    int st3 = __builtin_amdgcn_readfirstlane(s_tok[3]);
    float zc0 = sel6(st0), zc1 = sel6(st1);
    int   mk0 = (smb >> st0) & 1, mk1 = (smb >> st1) & 1;

    // per gate: 8 dot2 in 2 chains of depth 4 over the 16-unit slice
#define DOTG(g)                                                               \
        float pa##g = __builtin_amdgcn_fdot2(H0, wh##g##_0, 0.0f, false);     \
        float pb##g = __builtin_amdgcn_fdot2(H1, wh##g##_1, 0.0f, false);     \
        pa##g = __builtin_amdgcn_fdot2(H2, wh##g##_2, pa##g, false);          \
        pb##g = __builtin_amdgcn_fdot2(H3, wh##g##_3, pb##g, false);          \
        pa##g = __builtin_amdgcn_fdot2(H4, wh##g##_4, pa##g, false);          \
        pb##g = __builtin_amdgcn_fdot2(H5, wh##g##_5, pb##g, false);          \
        pa##g = __builtin_amdgcn_fdot2(H6, wh##g##_6, pa##g, false);          \
        pb##g = __builtin_amdgcn_fdot2(H7, wh##g##_7, pb##g, false);          \
        float p##g = pa##g + pb##g;

    // h-buffer safety: step t reads s_hh[RP] before its barrier (reads drain
    // at the barrier's lgkmcnt(0)); RP is rewritten only after that barrier.
#define STEP(RP, WP, ZC, MK)                                                  \
    {                                                                         \
        /* own 32B K-slice: 2x b128, 4 distinct addrs, 16-lane broadcast */   \
        const float4* hp = (const float4*)s_hh[RP];                           \
        const float4 hv0 = hp[s * 2 + 0];                                     \
        const float4 hv1 = hp[s * 2 + 1];                                     \
        const v2h H0 = as_v2h(hv0.x), H1 = as_v2h(hv0.y);                     \
        const v2h H2 = as_v2h(hv0.z), H3 = as_v2h(hv0.w);                     \
        const v2h H4 = as_v2h(hv1.x), H5 = as_v2h(hv1.y);                     \
        const v2h H6 = as_v2h(hv1.z), H7 = as_v2h(hv1.w);                     \
        DOTG(0) DOTG(1) DOTG(2) DOTG(3)                                       \
        /* transpose-butterfly (R12-verified): slice-sums -> own-gate z */    \
        p0 += dppf<kXor1>(p0); p1 += dppf<kXor1>(p1);                         \
        p2 += dppf<kXor1>(p2); p3 += dppf<kXor1>(p3);                         \
        float X = (s & 1) ? p1 : p0;                                          \
        float Y = (s & 1) ? p3 : p2;                                          \
        X += dppf<kXor2>(X); Y += dppf<kXor2>(Y);                             \
        const float z = ((s & 2) ? Y : X) + (ZC);                             \
        /* one activation per lane (own gate) */                              \
        const float e = exp2_f(z * aScale);                                   \
        const float r = fast_rcp(1.0f + e);                                   \
        const float a = fmaf(r, aMul, aAdd);                                  \
        /* quad broadcasts: gate q lives in lane q of the quad */             \
        const float ai = dppf<kBc0>(a);                                       \
        const float af = dppf<kBc1>(a);                                       \
        const float ag = dppf<kBc2>(a);                                       \
        const float ao = dppf<kBc3>(a);                                       \
        const float cn = fmaf(af, c, ai * ag);                                \
        const float hn = ao * tanh_f(cn);                                     \
        if (MK) { c = cn; hreg = hn; }   /* uniform branch */                 \
        if (s == 0) s_hh[WP][u] = (_Float16)hreg;                             \
        __syncthreads();                                                      \
    }

#pragma unroll 1
    for (int t = 0; t < kT; t += 2) {
        STEP(0, 1, zc0, mk0)
        // shadow work between barriers: next-pair token fetch (ONE b64
        // broadcast per 2 steps) + register proj selects for steps t+2,t+3
        const int2 vt = *((const int2*)(s_tok + ((t + 4) & (kT - 1))));
        const float zn0 = sel6(st2); const int mn0 = (smb >> st2) & 1;
        const float zn1 = sel6(st3); const int mn1 = (smb >> st3) & 1;
        STEP(1, 0, zc1, mk1)
        st2 = __builtin_amdgcn_readfirstlane(vt.x);
        st3 = __builtin_amdgcn_readfirstlane(vt.y);
        zc0 = zn0; zc1 = zn1; mk0 = mn0; mk1 = mn1;
    }
#undef STEP
#undef DOTG

    // ---- epilogue: quad lane s==0 holds exact f32 h_f[u], h_b[u] ----
    {
        float v = (s == 0) ? (hreg * Wd[u] + hb_val * Wd[kU + u]) : 0.0f;
#pragma unroll
        for (int off = 32; off > 0; off >>= 1) v += __shfl_down(v, off, 64);
        if (l == 0) s_red[wv] = v;
    }
    __syncthreads();
    if (tid == 0) out[b] = (s_red[0] + s_red[1]) + (s_red[2] + s_red[3]) + bd[0];
}

extern "C" void kernel_launch(void* const* d_in, const int* in_sizes, int n_in,
                              void* d_out, int out_size, void* d_ws, size_t ws_size,
                              hipStream_t stream) {
    const int*   tokens = (const int*)d_in[0];
    const float* emb    = (const float*)d_in[1];
    const float* Wk_f   = (const float*)d_in[2];
    const float* Wr_f   = (const float*)d_in[3];
    const float* b_f    = (const float*)d_in[4];
    const float* Wk_b   = (const float*)d_in[5];
    // d_in[6] = Wr_b: unused (backward runs one step from h0=0)
    const float* b_b    = (const float*)d_in[7];
    const float* Wd     = (const float*)d_in[8];
    const float* bd     = (const float*)d_in[9];
    float* out = (float*)d_out;

    bilstm_last_kernel<<<kB, 256, 0, stream>>>(
        tokens, emb, Wk_f, Wr_f, b_f, Wk_b, b_b, Wd, bd, out);
}